// Round 1
// baseline (359.207 us; speedup 1.0000x reference)
//
#include <hip/hip_runtime.h>

// Shapes (fixed by the reference):
//   x:  (N=32, C=384, H=56, W=56)  -> (n, c, p) with HW=3136 = 98*32
//   gf: (N=32, M=8, D=768)
//   W_kv: (E=768, D=768), b_kv: (768,)
//   kv[n][m][e] = clip(sum_d gf[n][m][d]*W[e][d] + b[e], 0, 6)
//   K = kv[..., :384], V = kv[..., 384:]
//   scores[n,p,k] = sum_c x[n,c,p]*K[n,k,c]; attn = softmax_k
//   out[n,c,p] = x[n,c,p] + sum_k attn[n,p,k]*V[n,k,c]

#define NC 384
#define HWP 3136
#define DD 768
#define MM 8
#define EE 768

// ---------------- Kernel 1: KV projection + ReLU6 (unchanged) ----------------
__global__ __launch_bounds__(256) void kv_kernel(const float* __restrict__ gf,
                                                 const float* __restrict__ Wk,
                                                 const float* __restrict__ bk,
                                                 float* __restrict__ kv) {
    __shared__ float g[MM * DD];  // 24 KB
    const int n = blockIdx.y;
    const int et = blockIdx.x;   // 0..11
    const int t = threadIdx.x;

    const float* gfn = gf + (size_t)n * (MM * DD);
    for (int i = t; i < MM * DD; i += 256) g[i] = gfn[i];
    __syncthreads();

    const int e = et * 64 + (t & 63);
    const int mb = (t >> 6) * 2;  // wave-uniform m pair

    const float4* w4 = (const float4*)(Wk + (size_t)e * DD);
    const float4* g0 = (const float4*)(g + (mb + 0) * DD);
    const float4* g1 = (const float4*)(g + (mb + 1) * DD);

    float a0 = 0.f, a1 = 0.f;
    #pragma unroll 8
    for (int i = 0; i < DD / 4; ++i) {
        const float4 w = w4[i];
        const float4 v0 = g0[i];
        const float4 v1 = g1[i];
        a0 += w.x * v0.x + w.y * v0.y + w.z * v0.z + w.w * v0.w;
        a1 += w.x * v1.x + w.y * v1.y + w.z * v1.z + w.w * v1.w;
    }
    const float bv = bk[e];
    float* o = kv + (size_t)n * (MM * EE);
    o[(mb + 0) * EE + e] = fminf(fmaxf(a0 + bv, 0.f), 6.f);
    o[(mb + 1) * EE + e] = fminf(fmaxf(a1 + bv, 0.f), 6.f);
}

// ---------------- Kernel 2: fused attention + residual ----------------
// grid (98, 32), block 256 = 4 waves. Block = (n, 32 positions).
// Wave = 8 positions x 8 channel-groups of 48 channels:
//   p_loc = lane & 7, g = lane >> 3, pos = tile*32 + w*8 + p_loc.
// Score reduction across channel groups is IN-WAVE (shfl_xor 8/16/32):
// no sc[] LDS buffer, no second barrier. One __syncthreads (kv staging only;
// x loads are issued after it so the barrier waits only on L2-fast kv loads).
// kvs layout: [half][k*416 + g*52 + j], j<48. Group stride 52 words:
// 8 ds_read_b128 addresses per wave cover banks {0,20,8,28,16,4,24,12}..+3
// = all 32 banks exactly once -> conflict-free, 8-lane broadcast each.
// LDS = 6656 floats = 26 KB -> 6 blocks/CU (vs 32 KB / 5 before).
// x kept in 48 VGPRs through the epilogue (no re-read).
__global__ __launch_bounds__(256, 6) void attn_kernel(const float* __restrict__ x,
                                                      const float* __restrict__ kv,
                                                      float* __restrict__ out) {
    __shared__ float kvs[6656];  // 26 KB

    const int n = blockIdx.y;
    const int tile = blockIdx.x;     // 0..97
    const int t = threadIdx.x;
    const int lane = t & 63;
    const int w = t >> 6;
    const int g = lane >> 3;             // channel group 0..7
    const int pos = tile * 32 + w * 8 + (lane & 7);
    const int c0 = g * 48;

    // stage this n's K/V into padded layout (float4 global + float4 LDS writes)
    const float4* kvn4 = (const float4*)(kv + (size_t)n * (MM * EE));
    #pragma unroll
    for (int r = 0; r < 6; ++r) {
        const int f = t + r * 256;        // float4 index 0..1535
        const int k = f / 192;
        const int e4 = f - k * 192;       // 0..191
        const int half = (e4 >= 96) ? 1 : 0;
        const int c4 = e4 - half * 96;    // 0..95
        const int g2 = c4 / 12;
        const int j4 = c4 - g2 * 12;
        *(float4*)&kvs[half * 3328 + k * 416 + g2 * 52 + j4 * 4] = kvn4[f];
    }
    __syncthreads();

    // stream my 48 channels x 1 position of x (issued post-barrier so the
    // barrier drain above only waited on the 6 L2-fast kv loads)
    const float* xp = x + (size_t)n * NC * HWP + (size_t)c0 * HWP + pos;
    float xr[48];
    #pragma unroll
    for (int i = 0; i < 48; ++i) xr[i] = xp[(size_t)i * HWP];

    // partial scores over my 48 channels (K as broadcast float4 LDS reads)
    float acc[8];
    #pragma unroll
    for (int k = 0; k < 8; ++k) acc[k] = 0.f;

    const float* kbase = &kvs[g * 52];
    #pragma unroll
    for (int i4 = 0; i4 < 12; ++i4) {
        const float x0 = xr[i4 * 4 + 0];
        const float x1 = xr[i4 * 4 + 1];
        const float x2 = xr[i4 * 4 + 2];
        const float x3 = xr[i4 * 4 + 3];
        #pragma unroll
        for (int k = 0; k < 8; ++k) {
            const float4 kk = *(const float4*)&kbase[k * 416 + i4 * 4];
            acc[k] += x0 * kk.x + x1 * kk.y + x2 * kk.z + x3 * kk.w;
        }
    }

    // in-wave reduce across the 8 channel groups (lane bits 3,4,5)
    #pragma unroll
    for (int k = 0; k < 8; ++k) {
        acc[k] += __shfl_xor(acc[k], 8, 64);
        acc[k] += __shfl_xor(acc[k], 16, 64);
        acc[k] += __shfl_xor(acc[k], 32, 64);
    }

    // softmax over k, fully per-thread (redundant x8 across groups, trivial)
    {
        float mx = acc[0];
        #pragma unroll
        for (int k = 1; k < 8; ++k) mx = fmaxf(mx, acc[k]);
        float su = 0.f;
        #pragma unroll
        for (int k = 0; k < 8; ++k) { acc[k] = __expf(acc[k] - mx); su += acc[k]; }
        const float inv = 1.f / su;
        #pragma unroll
        for (int k = 0; k < 8; ++k) acc[k] *= inv;
    }

    // epilogue: out = x + sum_k aw[k]*V[k][c]; xr is live, no x re-read
    float* op = out + (size_t)n * NC * HWP + (size_t)c0 * HWP + pos;
    const float* vbase = &kvs[3328 + g * 52];
    #pragma unroll
    for (int i4 = 0; i4 < 12; ++i4) {
        float o0 = xr[i4 * 4 + 0];
        float o1 = xr[i4 * 4 + 1];
        float o2 = xr[i4 * 4 + 2];
        float o3 = xr[i4 * 4 + 3];
        #pragma unroll
        for (int k = 0; k < 8; ++k) {
            const float4 vv = *(const float4*)&vbase[k * 416 + i4 * 4];
            o0 += acc[k] * vv.x;
            o1 += acc[k] * vv.y;
            o2 += acc[k] * vv.z;
            o3 += acc[k] * vv.w;
        }
        op[(size_t)(i4 * 4 + 0) * HWP] = o0;
        op[(size_t)(i4 * 4 + 1) * HWP] = o1;
        op[(size_t)(i4 * 4 + 2) * HWP] = o2;
        op[(size_t)(i4 * 4 + 3) * HWP] = o3;
    }
}

extern "C" void kernel_launch(void* const* d_in, const int* in_sizes, int n_in,
                              void* d_out, int out_size, void* d_ws, size_t ws_size,
                              hipStream_t stream) {
    const float* x  = (const float*)d_in[0];
    const float* gf = (const float*)d_in[1];
    const float* Wk = (const float*)d_in[2];
    const float* bk = (const float*)d_in[3];
    float* out = (float*)d_out;
    float* kv = (float*)d_ws;  // 32*8*768 floats = 768 KB

    kv_kernel<<<dim3(12, 32), 256, 0, stream>>>(gf, Wk, bk, kv);
    attn_kernel<<<dim3(98, 32), 256, 0, stream>>>(x, kv, out);
}